// Round 1
// 293.460 us; speedup vs baseline: 1.1659x; 1.1659x over previous
//
#include <hip/hip_runtime.h>
#include <math.h>

// S4 forward:
//   p[b,t] = u[b,t,:]·W_in          (K1, blocks 1..2048: 8 rows/wave, batched butterfly)
//   h[k]   = C·A_bar^k·B_bar        (K1, block 0: Taylor + squarings + U-doubling + V-chain)
//   sv[b,t]= D·p[b,t] + sum_{k<t} h[k]·p[b,t-1-k]   (K_conv, 512-thread blocks, conv only)
//   out[b,t,d] = sv[b,t]·W_out[d]   (K_out, 2048 blocks: pure streaming outer product)

#define S0 (Lh)
#define S1 (Lh + 4096)
#define S2 (Lh + 8192)
#define S3 (Lh + 12288)

// C[i0+r][j0+s] += sum_l XT[l][i0+r] * Y[l][j0+s]   (i.e. C = X·Y given X^T)
__device__ __forceinline__ void mm64_core(const float* XT, const float* Y,
                                          int i0, int j0, float c[4][4]) {
#pragma unroll 4
  for (int l = 0; l < 64; ++l) {
    float4 xv = *(const float4*)(XT + l * 64 + i0);
    float4 yv = *(const float4*)(Y + l * 64 + j0);
    c[0][0] += xv.x * yv.x; c[0][1] += xv.x * yv.y; c[0][2] += xv.x * yv.z; c[0][3] += xv.x * yv.w;
    c[1][0] += xv.y * yv.x; c[1][1] += xv.y * yv.y; c[1][2] += xv.y * yv.z; c[1][3] += xv.y * yv.w;
    c[2][0] += xv.z * yv.x; c[2][1] += xv.z * yv.y; c[2][2] += xv.z * yv.z; c[2][3] += xv.z * yv.w;
    c[3][0] += xv.w * yv.x; c[3][1] += xv.w * yv.y; c[3][2] += xv.w * yv.z; c[3][3] += xv.w * yv.w;
  }
}

__device__ __forceinline__ void store_tile(float* Cp, int i0, int j0, float c[4][4]) {
#pragma unroll
  for (int r = 0; r < 4; ++r)
    *(float4*)(Cp + (i0 + r) * 64 + j0) = make_float4(c[r][0], c[r][1], c[r][2], c[r][3]);
}

// 63-step matvec chain (single wave, wave-synchronous LDS round-trip, NO volatile):
// v_{j+1}[ln] = dot(rowsrc row ln, v_j); outT[ln][j] = v_j[ln].
__device__ __forceinline__ void chain64(const float* rowsrc, float* ubuf,
                                        float* outT, int ln, float v0) {
  float row[64];
#pragma unroll
  for (int q = 0; q < 16; ++q) {
    float4 rv = *(const float4*)(rowsrc + ln * 64 + 4 * q);
    row[4 * q] = rv.x; row[4 * q + 1] = rv.y; row[4 * q + 2] = rv.z; row[4 * q + 3] = rv.w;
  }
  float v = v0;
  for (int jq = 0; jq < 16; ++jq) {
    float q0 = v, q1, q2, q3;
#pragma unroll
    for (int m = 1; m < 4; ++m) {
      ubuf[ln] = v;
      __builtin_amdgcn_wave_barrier();
      float a0 = 0.f, a1 = 0.f, a2 = 0.f, a3 = 0.f;
#pragma unroll
      for (int q = 0; q < 16; ++q) {
        float4 uv = *(const float4*)(ubuf + 4 * q);
        a0 += row[4 * q] * uv.x; a1 += row[4 * q + 1] * uv.y;
        a2 += row[4 * q + 2] * uv.z; a3 += row[4 * q + 3] * uv.w;
      }
      __builtin_amdgcn_wave_barrier();
      v = (a0 + a1) + (a2 + a3);
      if (m == 1) q1 = v; else if (m == 2) q2 = v; else q3 = v;
    }
    *(float4*)(outT + ln * 64 + 4 * jq) = make_float4(q0, q1, q2, q3);
    if (jq < 15) {
      ubuf[ln] = v;
      __builtin_amdgcn_wave_barrier();
      float a0 = 0.f, a1 = 0.f, a2 = 0.f, a3 = 0.f;
#pragma unroll
      for (int q = 0; q < 16; ++q) {
        float4 uv = *(const float4*)(ubuf + 4 * q);
        a0 += row[4 * q] * uv.x; a1 += row[4 * q + 1] * uv.y;
        a2 += row[4 * q + 2] * uv.z; a3 += row[4 * q + 3] * uv.w;
      }
      __builtin_amdgcn_wave_barrier();
      v = (a0 + a1) + (a2 + a3);
    }
  }
}

extern "C" __global__ __launch_bounds__(256) void s4_k1(
    const float* __restrict__ u, const float* __restrict__ A, const float* __restrict__ B,
    const float* __restrict__ C, const float* __restrict__ logdt, const float* __restrict__ Win,
    float* __restrict__ p_ws, float* __restrict__ h_ws) {
  __shared__ __align__(16) float Lh[16384];  // 4 slots of 64x64 f32
  __shared__ __align__(16) float cbuf[64];   // chain round-trip buffer
  const int tid = threadIdx.x;

  if (blockIdx.x == 0) {
    // ================= h[k] pipeline (one block) =================
    float dt = expf(logdt[0]);
    dt = fminf(fmaxf(dt, 0.001f), 0.1f);

    // load dA = dt*A into S0 (row-major) and dAT into S1
#pragma unroll
    for (int n = 0; n < 16; ++n) {
      int e = tid * 16 + n;
      int i = e >> 6, j = e & 63;
      float v = A[e] * dt;
      S0[e] = v;
      S1[j * 64 + i] = v;
    }
    __syncthreads();

    const int i0 = (tid & 15) << 2, j0 = (tid >> 4) << 2;
    const int bi = tid & 63, bq = tid >> 6;
    const int wv = tid >> 6, ln = tid & 63;

    // A_bar tile accumulator: I + dA + sum_{k=2..5} dA^k/k!
    float ab[4][4];
#pragma unroll
    for (int r = 0; r < 4; ++r) {
      float4 da = *(const float4*)(S0 + (i0 + r) * 64 + j0);
      ab[r][0] = da.x + ((i0 + r) == (j0 + 0) ? 1.f : 0.f);
      ab[r][1] = da.y + ((i0 + r) == (j0 + 1) ? 1.f : 0.f);
      ab[r][2] = da.z + ((i0 + r) == (j0 + 2) ? 1.f : 0.f);
      ab[r][3] = da.w + ((i0 + r) == (j0 + 3) ? 1.f : 0.f);
    }

    // B_bar partials: bbp(i,q) = sum_k 1/(k+1)! * sum_{m in q-quarter} dA^k[i][l]*B[l]
    float Bv[16];
#pragma unroll
    for (int m = 0; m < 16; m += 4) {
      float4 b4 = *(const float4*)(B + bq * 16 + m);
      Bv[m] = b4.x; Bv[m + 1] = b4.y; Bv[m + 2] = b4.z; Bv[m + 3] = b4.w;
    }
    float bbp = (bq == (bi >> 4)) ? B[bi] : 0.f;  // k=0 term
#pragma unroll
    for (int m = 0; m < 16; m += 4) {
      float4 a4 = *(const float4*)(S0 + bi * 64 + bq * 16 + m);
      bbp += 0.5f * (a4.x * Bv[m] + a4.y * Bv[m + 1] + a4.z * Bv[m + 2] + a4.w * Bv[m + 3]);
    }

    // Taylor K=5 (||dA|| ~ 0.035 -> truncation ~3e-12): ping-pong S1<->S2
    float fact = 1.f;
    int ping = 1;
    for (int k = 2; k <= 5; ++k) {
      const float* Yp = Lh + 4096 * ping;
      float* Cp = Lh + 4096 * (3 - ping);
      float c[4][4] = {{0.f}};
      mm64_core(S0, Yp, i0, j0, c);
      store_tile(Cp, i0, j0, c);
      __syncthreads();
      fact *= (float)k;
      float ivf = 1.f / fact;
      float ivf1 = ivf / (float)(k + 1);
#pragma unroll
      for (int s = 0; s < 4; ++s) {
        float4 pv = *(const float4*)(Cp + (j0 + s) * 64 + i0);
        ab[0][s] += pv.x * ivf; ab[1][s] += pv.y * ivf;
        ab[2][s] += pv.z * ivf; ab[3][s] += pv.w * ivf;
      }
#pragma unroll
      for (int m = 0; m < 16; ++m)
        bbp += ivf1 * Cp[(bq * 16 + m) * 64 + bi] * Bv[m];
      ping = 3 - ping;
    }
    // combine bbp -> wave0 registers (B_bar)
    __syncthreads();
    S1[bq * 64 + bi] = bbp;
    __syncthreads();
    float breg = 0.f;
    if (tid < 64)
      breg = dt * (S1[tid] + S1[64 + tid] + S1[128 + tid] + S1[192 + tid]);
    __syncthreads();
    // AB -> S1, ABT -> S2
    store_tile(S1, i0, j0, ab);
#pragma unroll
    for (int s = 0; s < 4; ++s)
      *(float4*)(S2 + (j0 + s) * 64 + i0) = make_float4(ab[0][s], ab[1][s], ab[2][s], ab[3][s]);
    __syncthreads();

    // Seed UT cols 0..3 (wave 0): U_0=C, U_{j+1} = U_j·AB via ABT rows
    if (wv == 0) {
      float uq0, uq1, uq2, uq3;
      float uv = C[ln];
      uq0 = uv;
#pragma unroll
      for (int stp = 1; stp < 4; ++stp) {
        cbuf[ln] = uv;
        __builtin_amdgcn_wave_barrier();
        float a0 = 0.f, a1 = 0.f, a2 = 0.f, a3 = 0.f;
#pragma unroll
        for (int q = 0; q < 16; ++q) {
          float4 rv = *(const float4*)(S2 + ln * 64 + 4 * q);
          float4 xv = *(const float4*)(cbuf + 4 * q);
          a0 += rv.x * xv.x; a1 += rv.y * xv.y; a2 += rv.z * xv.z; a3 += rv.w * xv.w;
        }
        __builtin_amdgcn_wave_barrier();
        uv = (a0 + a1) + (a2 + a3);
        if (stp == 1) uq1 = uv; else if (stp == 2) uq2 = uv; else uq3 = uv;
      }
      *(float4*)(S3 + ln * 64) = make_float4(uq0, uq1, uq2, uq3);
    }
    __syncthreads();

    // Squarings AB -> A64, with U-doubling folded in:
    // after sq s (result M_{2^{s+1}}), rows [R,2R) of U = U[0,R)·M_R for R=4<<(s-1)
    int sM = 1, sT = 2, sF = 0;
    for (int sq = 0; sq < 6; ++sq) {
      {
        float c[4][4] = {{0.f}};
        mm64_core(Lh + 4096 * sT, Lh + 4096 * sM, i0, j0, c);
        store_tile(Lh + 4096 * sF, i0, j0, c);
      }
      __syncthreads();
      if (sq >= 1 && sq <= 4) {
        const int R = 4 << (sq - 1);
        if (i0 < R) {
          float c2[4][4] = {{0.f}};
          mm64_core(S3, Lh + 4096 * sF, i0, j0, c2);
#pragma unroll
          for (int s = 0; s < 4; ++s)
            *(float4*)(S3 + (j0 + s) * 64 + R + i0) =
                make_float4(c2[0][s], c2[1][s], c2[2][s], c2[3][s]);
        }
      }
      if (sq < 5) {
        const float* F = Lh + 4096 * sF;
        float* Dst = Lh + 4096 * sM;
        float4 v0 = *(const float4*)(F + (i0 + 0) * 64 + j0);
        float4 v1 = *(const float4*)(F + (i0 + 1) * 64 + j0);
        float4 v2 = *(const float4*)(F + (i0 + 2) * 64 + j0);
        float4 v3 = *(const float4*)(F + (i0 + 3) * 64 + j0);
        *(float4*)(Dst + (j0 + 0) * 64 + i0) = make_float4(v0.x, v1.x, v2.x, v3.x);
        *(float4*)(Dst + (j0 + 1) * 64 + i0) = make_float4(v0.y, v1.y, v2.y, v3.y);
        *(float4*)(Dst + (j0 + 2) * 64 + i0) = make_float4(v0.z, v1.z, v2.z, v3.z);
        *(float4*)(Dst + (j0 + 3) * 64 + i0) = make_float4(v0.w, v1.w, v2.w, v3.w);
        __syncthreads();
        int nM = sF, nT = sM, nF = sT;
        sM = nM; sT = nT; sF = nF;
      }
    }
    // A64 row-major in S1.  Dead: S0, S2.  UT alive in S3.
    // V-chain (wave 0): V[l][m] = (A64^m·B_bar)[l] -> S0
    if (wv == 0) chain64(S1, cbuf, S0, ln, breg);
    __syncthreads();

    // H[j][m] = sum_l UT[l][j]*V[l][m] = h[64m + j]  -> global
    {
      float c[4][4] = {{0.f}};
      mm64_core(S3, S0, i0, j0, c);
#pragma unroll
      for (int s = 0; s < 4; ++s)
        *(float4*)(h_ws + 64 * (j0 + s) + i0) = make_float4(c[0][s], c[1][s], c[2][s], c[3][s]);
    }
  } else {
    // ===== p[b,t] = u·W_in (2048 blocks, 8 rows/wave, batched butterfly) =====
    const int pb = blockIdx.x - 1;           // 0..2047
    const int ln = tid & 63;
    const int g = (pb << 2) | (tid >> 6);    // global wave id, 0..8191
    float4 w0 = *(const float4*)(Win + ln * 8);
    float4 w1 = *(const float4*)(Win + ln * 8 + 4);
    const size_t base = (size_t)g * 8 * 512 + (size_t)ln * 8;
    float acc[8];
#pragma unroll
    for (int i = 0; i < 8; ++i) {
      const float* up = u + base + (size_t)i * 512;
      float4 a0 = *(const float4*)up;
      float4 a1 = *(const float4*)(up + 4);
      acc[i] = a0.x * w0.x + a0.y * w0.y + a0.z * w0.z + a0.w * w0.w +
               a1.x * w1.x + a1.y * w1.y + a1.z * w1.z + a1.w * w1.w;
    }
    // 6 butterfly rounds, 8 independent chains per round -> ILP hides shfl latency
#pragma unroll
    for (int off = 32; off > 0; off >>= 1) {
#pragma unroll
      for (int i = 0; i < 8; ++i) acc[i] += __shfl_xor(acc[i], off);
    }
    if (ln == 0) {
      *(float4*)(p_ws + (g << 3)) = make_float4(acc[0], acc[1], acc[2], acc[3]);
      *(float4*)(p_ws + (g << 3) + 4) = make_float4(acc[4], acc[5], acc[6], acc[7]);
    }
  }
}

// conv only: sv[b,t] = D*p[b,t] + sum_{k<t} h[k]*p[b,t-1-k]
extern "C" __global__ __launch_bounds__(512) void s4_conv(
    const float* __restrict__ p_ws, const float* __restrict__ h_ws,
    const float* __restrict__ Dp, float* __restrict__ sv_ws) {
  __shared__ __align__(16) float hpad[4352];  // [0..255]=0 pad, [256+k]=h[k]
  __shared__ __align__(16) float ps[4096];    // p[b, 0..4095]
  __shared__ __align__(16) float part[2048];  // per-wave partial s (8 waves)
  const int tid = threadIdx.x;
  const int b = blockIdx.x >> 4, tile = blockIdx.x & 15;

  if (tid < 256) hpad[tid] = 0.f;
#pragma unroll
  for (int i = 0; i < 2; ++i) {
    int idx = i * 2048 + tid * 4;
    *(float4*)(hpad + 256 + idx) = *(const float4*)(h_ws + idx);
    *(float4*)(ps + idx) = *(const float4*)(p_ws + (b << 12) + idx);
  }
  __syncthreads();

  // conv: lane owns outputs t = t0 + 4*ln + {0..3}; 8 waves partition chunks c.
  const int wv = tid >> 6, ln = tid & 63;
  const int t0 = tile << 8;
  float a0 = 0.f, a1 = 0.f, a2 = 0.f, a3 = 0.f;
  for (int c = wv; c <= tile; c += 8) {
    // W(k) = t0 + 4*ln - 1 - 256c - k; hA = h[W-3..W], hB = h[W+1..W+4], 16B-aligned
    const float* pA = hpad + 256 + t0 + 4 * ln - 4 - (c << 8);
    const float* pc = ps + (c << 8);
#pragma unroll 4
    for (int k = 0; k < 256; k += 4) {
      float4 p4 = *(const float4*)(pc + k);      // broadcast
      float4 hA = *(const float4*)(pA - k);
      float4 hB = *(const float4*)(pA - k + 4);
      a0 += p4.x * hA.w + p4.y * hA.z + p4.z * hA.y + p4.w * hA.x;
      a1 += p4.x * hB.x + p4.y * hA.w + p4.z * hA.z + p4.w * hA.y;
      a2 += p4.x * hB.y + p4.y * hB.x + p4.z * hA.w + p4.w * hA.z;
      a3 += p4.x * hB.z + p4.y * hB.y + p4.z * hB.x + p4.w * hA.w;
    }
  }
  *(float4*)(part + (wv << 8) + (ln << 2)) = make_float4(a0, a1, a2, a3);
  __syncthreads();
  if (tid < 256) {
    float s = Dp[0] * ps[t0 + tid];
#pragma unroll
    for (int w = 0; w < 8; ++w) s += part[w * 256 + tid];
    sv_ws[(b << 12) + t0 + tid] = s;
  }
}

// pure streaming epilogue: out[b,t,:] = sv[b,t] * W_out[:]
extern "C" __global__ __launch_bounds__(256) void s4_out(
    const float* __restrict__ sv_ws, const float* __restrict__ Wout,
    float* __restrict__ out) {
  const int tid = threadIdx.x;
  const int ln = tid & 63;
  const int g = (blockIdx.x << 2) | (tid >> 6);  // global wave id, 0..8191
  float4 wa = *(const float4*)(Wout + ln * 8);
  float4 wb = *(const float4*)(Wout + ln * 8 + 4);
  // lanes 0..7 hold sv for the wave's 8 rows; broadcast via shfl
  float myv = sv_ws[(g << 3) + (ln & 7)];
  float* op0 = out + (size_t)(g << 3) * 512 + (size_t)ln * 8;
#pragma unroll
  for (int i = 0; i < 8; ++i) {
    float s = __shfl(myv, i);
    float* op = op0 + (size_t)i * 512;
    *(float4*)op = make_float4(s * wa.x, s * wa.y, s * wa.z, s * wa.w);
    *(float4*)(op + 4) = make_float4(s * wb.x, s * wb.y, s * wb.z, s * wb.w);
  }
}

extern "C" void kernel_launch(void* const* d_in, const int* in_sizes, int n_in,
                              void* d_out, int out_size, void* d_ws, size_t ws_size,
                              hipStream_t stream) {
  const float* u = (const float*)d_in[0];
  const float* A = (const float*)d_in[1];
  const float* B = (const float*)d_in[2];
  const float* C = (const float*)d_in[3];
  const float* D = (const float*)d_in[4];
  const float* logdt = (const float*)d_in[5];
  const float* Win = (const float*)d_in[6];
  const float* Wout = (const float*)d_in[7];
  float* outp = (float*)d_out;
  float* p_ws = (float*)d_ws;        // 65536 floats
  float* h_ws = p_ws + 65536;        // 4096 floats
  float* sv_ws = h_ws + 4096;        // 65536 floats

  s4_k1<<<2049, 256, 0, stream>>>(u, A, B, C, logdt, Win, p_ws, h_ws);
  s4_conv<<<256, 512, 0, stream>>>(p_ws, h_ws, D, sv_ws);
  s4_out<<<2048, 256, 0, stream>>>(sv_ws, Wout, outp);
}

// Round 3
// 273.588 us; speedup vs baseline: 1.2505x; 1.0726x over previous
//
#include <hip/hip_runtime.h>
#include <math.h>

// S4 forward:
//   p[b,t] = u[b,t,:]·W_in          (K1, blocks 1..2048: 8 rows/wave, batched butterfly)
//   h[k]   = C·A_bar^k·B_bar        (K1, block 0: Taylor + squarings + U-doubling + V-chain)
//   out[b,t,:] = (D·p[b,t] + sum_{k<t} h[k]·p[b,t-1-k]) · W_out
//                                    (K_co, 2048 blocks x 512 thr: 32-row tiles,
//                                     tiny conv fused directly into the output stream)

#define S0 (Lh)
#define S1 (Lh + 4096)
#define S2 (Lh + 8192)
#define S3 (Lh + 12288)

// C[i0+r][j0+s] += sum_l XT[l][i0+r] * Y[l][j0+s]   (i.e. C = X·Y given X^T)
__device__ __forceinline__ void mm64_core(const float* XT, const float* Y,
                                          int i0, int j0, float c[4][4]) {
#pragma unroll 4
  for (int l = 0; l < 64; ++l) {
    float4 xv = *(const float4*)(XT + l * 64 + i0);
    float4 yv = *(const float4*)(Y + l * 64 + j0);
    c[0][0] += xv.x * yv.x; c[0][1] += xv.x * yv.y; c[0][2] += xv.x * yv.z; c[0][3] += xv.x * yv.w;
    c[1][0] += xv.y * yv.x; c[1][1] += xv.y * yv.y; c[1][2] += xv.y * yv.z; c[1][3] += xv.y * yv.w;
    c[2][0] += xv.z * yv.x; c[2][1] += xv.z * yv.y; c[2][2] += xv.z * yv.z; c[2][3] += xv.z * yv.w;
    c[3][0] += xv.w * yv.x; c[3][1] += xv.w * yv.y; c[3][2] += xv.w * yv.z; c[3][3] += xv.w * yv.w;
  }
}

__device__ __forceinline__ void store_tile(float* Cp, int i0, int j0, float c[4][4]) {
#pragma unroll
  for (int r = 0; r < 4; ++r)
    *(float4*)(Cp + (i0 + r) * 64 + j0) = make_float4(c[r][0], c[r][1], c[r][2], c[r][3]);
}

// 63-step matvec chain (single wave, wave-synchronous LDS round-trip, NO volatile):
// v_{j+1}[ln] = dot(rowsrc row ln, v_j); outT[ln][j] = v_j[ln].
__device__ __forceinline__ void chain64(const float* rowsrc, float* ubuf,
                                        float* outT, int ln, float v0) {
  float row[64];
#pragma unroll
  for (int q = 0; q < 16; ++q) {
    float4 rv = *(const float4*)(rowsrc + ln * 64 + 4 * q);
    row[4 * q] = rv.x; row[4 * q + 1] = rv.y; row[4 * q + 2] = rv.z; row[4 * q + 3] = rv.w;
  }
  float v = v0;
  for (int jq = 0; jq < 16; ++jq) {
    float q0 = v, q1, q2, q3;
#pragma unroll
    for (int m = 1; m < 4; ++m) {
      ubuf[ln] = v;
      __builtin_amdgcn_wave_barrier();
      float a0 = 0.f, a1 = 0.f, a2 = 0.f, a3 = 0.f;
#pragma unroll
      for (int q = 0; q < 16; ++q) {
        float4 uv = *(const float4*)(ubuf + 4 * q);
        a0 += row[4 * q] * uv.x; a1 += row[4 * q + 1] * uv.y;
        a2 += row[4 * q + 2] * uv.z; a3 += row[4 * q + 3] * uv.w;
      }
      __builtin_amdgcn_wave_barrier();
      v = (a0 + a1) + (a2 + a3);
      if (m == 1) q1 = v; else if (m == 2) q2 = v; else q3 = v;
    }
    *(float4*)(outT + ln * 64 + 4 * jq) = make_float4(q0, q1, q2, q3);
    if (jq < 15) {
      ubuf[ln] = v;
      __builtin_amdgcn_wave_barrier();
      float a0 = 0.f, a1 = 0.f, a2 = 0.f, a3 = 0.f;
#pragma unroll
      for (int q = 0; q < 16; ++q) {
        float4 uv = *(const float4*)(ubuf + 4 * q);
        a0 += row[4 * q] * uv.x; a1 += row[4 * q + 1] * uv.y;
        a2 += row[4 * q + 2] * uv.z; a3 += row[4 * q + 3] * uv.w;
      }
      __builtin_amdgcn_wave_barrier();
      v = (a0 + a1) + (a2 + a3);
    }
  }
}

extern "C" __global__ __launch_bounds__(256) void s4_k1(
    const float* __restrict__ u, const float* __restrict__ A, const float* __restrict__ B,
    const float* __restrict__ C, const float* __restrict__ logdt, const float* __restrict__ Win,
    float* __restrict__ p_ws, float* __restrict__ h_ws) {
  __shared__ __align__(16) float Lh[16384];  // 4 slots of 64x64 f32
  __shared__ __align__(16) float cbuf[64];   // chain round-trip buffer
  const int tid = threadIdx.x;

  if (blockIdx.x == 0) {
    // ================= h[k] pipeline (one block) =================
    float dt = expf(logdt[0]);
    dt = fminf(fmaxf(dt, 0.001f), 0.1f);

    // load dA = dt*A into S0 (row-major) and dAT into S1
#pragma unroll
    for (int n = 0; n < 16; ++n) {
      int e = tid * 16 + n;
      int i = e >> 6, j = e & 63;
      float v = A[e] * dt;
      S0[e] = v;
      S1[j * 64 + i] = v;
    }
    __syncthreads();

    const int i0 = (tid & 15) << 2, j0 = (tid >> 4) << 2;
    const int bi = tid & 63, bq = tid >> 6;
    const int wv = tid >> 6, ln = tid & 63;

    // A_bar tile accumulator: I + dA + sum_{k=2..5} dA^k/k!
    float ab[4][4];
#pragma unroll
    for (int r = 0; r < 4; ++r) {
      float4 da = *(const float4*)(S0 + (i0 + r) * 64 + j0);
      ab[r][0] = da.x + ((i0 + r) == (j0 + 0) ? 1.f : 0.f);
      ab[r][1] = da.y + ((i0 + r) == (j0 + 1) ? 1.f : 0.f);
      ab[r][2] = da.z + ((i0 + r) == (j0 + 2) ? 1.f : 0.f);
      ab[r][3] = da.w + ((i0 + r) == (j0 + 3) ? 1.f : 0.f);
    }

    // B_bar partials: bbp(i,q) = sum_k 1/(k+1)! * sum_{m in q-quarter} dA^k[i][l]*B[l]
    float Bv[16];
#pragma unroll
    for (int m = 0; m < 16; m += 4) {
      float4 b4 = *(const float4*)(B + bq * 16 + m);
      Bv[m] = b4.x; Bv[m + 1] = b4.y; Bv[m + 2] = b4.z; Bv[m + 3] = b4.w;
    }
    float bbp = (bq == (bi >> 4)) ? B[bi] : 0.f;  // k=0 term
#pragma unroll
    for (int m = 0; m < 16; m += 4) {
      float4 a4 = *(const float4*)(S0 + bi * 64 + bq * 16 + m);
      bbp += 0.5f * (a4.x * Bv[m] + a4.y * Bv[m + 1] + a4.z * Bv[m + 2] + a4.w * Bv[m + 3]);
    }

    // Taylor K=5 (||dA|| ~ 0.035 -> truncation ~3e-12): ping-pong S1<->S2
    float fact = 1.f;
    int ping = 1;
    for (int k = 2; k <= 5; ++k) {
      const float* Yp = Lh + 4096 * ping;
      float* Cp = Lh + 4096 * (3 - ping);
      float c[4][4] = {{0.f}};
      mm64_core(S0, Yp, i0, j0, c);
      store_tile(Cp, i0, j0, c);
      __syncthreads();
      fact *= (float)k;
      float ivf = 1.f / fact;
      float ivf1 = ivf / (float)(k + 1);
#pragma unroll
      for (int s = 0; s < 4; ++s) {
        float4 pv = *(const float4*)(Cp + (j0 + s) * 64 + i0);
        ab[0][s] += pv.x * ivf; ab[1][s] += pv.y * ivf;
        ab[2][s] += pv.z * ivf; ab[3][s] += pv.w * ivf;
      }
#pragma unroll
      for (int m = 0; m < 16; ++m)
        bbp += ivf1 * Cp[(bq * 16 + m) * 64 + bi] * Bv[m];
      ping = 3 - ping;
    }
    // combine bbp -> wave0 registers (B_bar)
    __syncthreads();
    S1[bq * 64 + bi] = bbp;
    __syncthreads();
    float breg = 0.f;
    if (tid < 64)
      breg = dt * (S1[tid] + S1[64 + tid] + S1[128 + tid] + S1[192 + tid]);
    __syncthreads();
    // AB -> S1, ABT -> S2
    store_tile(S1, i0, j0, ab);
#pragma unroll
    for (int s = 0; s < 4; ++s)
      *(float4*)(S2 + (j0 + s) * 64 + i0) = make_float4(ab[0][s], ab[1][s], ab[2][s], ab[3][s]);
    __syncthreads();

    // Seed UT cols 0..3 (wave 0): U_0=C, U_{j+1} = U_j·AB via ABT rows
    if (wv == 0) {
      float uq0, uq1, uq2, uq3;
      float uv = C[ln];
      uq0 = uv;
#pragma unroll
      for (int stp = 1; stp < 4; ++stp) {
        cbuf[ln] = uv;
        __builtin_amdgcn_wave_barrier();
        float a0 = 0.f, a1 = 0.f, a2 = 0.f, a3 = 0.f;
#pragma unroll
        for (int q = 0; q < 16; ++q) {
          float4 rv = *(const float4*)(S2 + ln * 64 + 4 * q);
          float4 xv = *(const float4*)(cbuf + 4 * q);
          a0 += rv.x * xv.x; a1 += rv.y * xv.y; a2 += rv.z * xv.z; a3 += rv.w * xv.w;
        }
        __builtin_amdgcn_wave_barrier();
        uv = (a0 + a1) + (a2 + a3);
        if (stp == 1) uq1 = uv; else if (stp == 2) uq2 = uv; else uq3 = uv;
      }
      *(float4*)(S3 + ln * 64) = make_float4(uq0, uq1, uq2, uq3);
    }
    __syncthreads();

    // Squarings AB -> A64, with U-doubling folded in:
    // after sq s (result M_{2^{s+1}}), rows [R,2R) of U = U[0,R)·M_R for R=4<<(s-1)
    int sM = 1, sT = 2, sF = 0;
    for (int sq = 0; sq < 6; ++sq) {
      {
        float c[4][4] = {{0.f}};
        mm64_core(Lh + 4096 * sT, Lh + 4096 * sM, i0, j0, c);
        store_tile(Lh + 4096 * sF, i0, j0, c);
      }
      __syncthreads();
      if (sq >= 1 && sq <= 4) {
        const int R = 4 << (sq - 1);
        if (i0 < R) {
          float c2[4][4] = {{0.f}};
          mm64_core(S3, Lh + 4096 * sF, i0, j0, c2);
#pragma unroll
          for (int s = 0; s < 4; ++s)
            *(float4*)(S3 + (j0 + s) * 64 + R + i0) =
                make_float4(c2[0][s], c2[1][s], c2[2][s], c2[3][s]);
        }
      }
      if (sq < 5) {
        const float* F = Lh + 4096 * sF;
        float* Dst = Lh + 4096 * sM;
        float4 v0 = *(const float4*)(F + (i0 + 0) * 64 + j0);
        float4 v1 = *(const float4*)(F + (i0 + 1) * 64 + j0);
        float4 v2 = *(const float4*)(F + (i0 + 2) * 64 + j0);
        float4 v3 = *(const float4*)(F + (i0 + 3) * 64 + j0);
        *(float4*)(Dst + (j0 + 0) * 64 + i0) = make_float4(v0.x, v1.x, v2.x, v3.x);
        *(float4*)(Dst + (j0 + 1) * 64 + i0) = make_float4(v0.y, v1.y, v2.y, v3.y);
        *(float4*)(Dst + (j0 + 2) * 64 + i0) = make_float4(v0.z, v1.z, v2.z, v3.z);
        *(float4*)(Dst + (j0 + 3) * 64 + i0) = make_float4(v0.w, v1.w, v2.w, v3.w);
        __syncthreads();
        int nM = sF, nT = sM, nF = sT;
        sM = nM; sT = nT; sF = nF;
      }
    }
    // A64 row-major in S1.  Dead: S0, S2.  UT alive in S3.
    // V-chain (wave 0): V[l][m] = (A64^m·B_bar)[l] -> S0
    if (wv == 0) chain64(S1, cbuf, S0, ln, breg);
    __syncthreads();

    // H[j][m] = sum_l UT[l][j]*V[l][m] = h[64m + j]  -> global
    {
      float c[4][4] = {{0.f}};
      mm64_core(S3, S0, i0, j0, c);
#pragma unroll
      for (int s = 0; s < 4; ++s)
        *(float4*)(h_ws + 64 * (j0 + s) + i0) = make_float4(c[0][s], c[1][s], c[2][s], c[3][s]);
    }
  } else {
    // ===== p[b,t] = u·W_in (2048 blocks, 8 rows/wave, batched butterfly) =====
    const int pb = blockIdx.x - 1;           // 0..2047
    const int ln = tid & 63;
    const int g = (pb << 2) | (tid >> 6);    // global wave id, 0..8191
    float4 w0 = *(const float4*)(Win + ln * 8);
    float4 w1 = *(const float4*)(Win + ln * 8 + 4);
    const size_t base = (size_t)g * 8 * 512 + (size_t)ln * 8;
    float acc[8];
#pragma unroll
    for (int i = 0; i < 8; ++i) {
      const float* up = u + base + (size_t)i * 512;
      float4 a0 = *(const float4*)up;
      float4 a1 = *(const float4*)(up + 4);
      acc[i] = a0.x * w0.x + a0.y * w0.y + a0.z * w0.z + a0.w * w0.w +
               a1.x * w1.x + a1.y * w1.y + a1.z * w1.z + a1.w * w1.w;
    }
    // 6 butterfly rounds, 8 independent chains per round -> ILP hides shfl latency
#pragma unroll
    for (int off = 32; off > 0; off >>= 1) {
#pragma unroll
      for (int i = 0; i < 8; ++i) acc[i] += __shfl_xor(acc[i], off);
    }
    if (ln == 0) {
      *(float4*)(p_ws + (g << 3)) = make_float4(acc[0], acc[1], acc[2], acc[3]);
      *(float4*)(p_ws + (g << 3) + 4) = make_float4(acc[4], acc[5], acc[6], acc[7]);
    }
  }
}

// Fused conv + output stream.  Grid: 16 b x 128 tiles of 32 rows, 512 threads.
// sv[t0+o] = D*p[t0+o] + sum_{k<t} h[k]*p[t-1-k]; out[b,t,:] = sv*W_out.
extern "C" __global__ __launch_bounds__(512) void s4_co(
    const float* __restrict__ p_ws, const float* __restrict__ h_ws,
    const float* __restrict__ Dp, const float* __restrict__ Wout,
    float* __restrict__ out) {
  __shared__ __align__(16) float hpad[4608];  // [0..511]=0 pad, [512+k]=h[k]
  __shared__ __align__(16) float ps[4096];    // p[b, 0..4095]
  __shared__ __align__(16) float part[2048];  // 8 waves x 64 lanes x 4
  __shared__ __align__(16) float svs[32];
  const int tid = threadIdx.x;
  const int b = blockIdx.x >> 7, tile = blockIdx.x & 127;
  const int t0 = tile << 5;

  if (tid < 128) *(float4*)(hpad + tid * 4) = make_float4(0.f, 0.f, 0.f, 0.f);
  *(float4*)(hpad + 512 + tid * 8) = *(const float4*)(h_ws + tid * 8);
  *(float4*)(hpad + 512 + tid * 8 + 4) = *(const float4*)(h_ws + tid * 8 + 4);
  *(float4*)(ps + tid * 8) = *(const float4*)(p_ws + (b << 12) + tid * 8);
  *(float4*)(ps + tid * 8 + 4) = *(const float4*)(p_ws + (b << 12) + tid * 8 + 4);
  __syncthreads();

  // conv: lane owns outputs t0 + 4*og + {0..3}, k-subgroup kg of 32 within each
  // 256-wide chunk c; 8 waves partition chunks.
  const int wv = tid >> 6, ln = tid & 63;
  const int og = ln & 7, kg = ln >> 3;
  const int cmax = (t0 + 31) >> 8;
  float a0 = 0.f, a1 = 0.f, a2 = 0.f, a3 = 0.f;
  for (int c = wv; c <= cmax; c += 8) {
    const float* pA = hpad + 512 + t0 + 4 * og - 4 - (c << 8) - (kg << 5);
    const float* pc = ps + (c << 8) + (kg << 5);
#pragma unroll
    for (int k = 0; k < 32; k += 4) {
      float4 p4 = *(const float4*)(pc + k);      // broadcast
      float4 hA = *(const float4*)(pA - k);
      float4 hB = *(const float4*)(pA - k + 4);
      a0 += p4.x * hA.w + p4.y * hA.z + p4.z * hA.y + p4.w * hA.x;
      a1 += p4.x * hB.x + p4.y * hA.w + p4.z * hA.z + p4.w * hA.y;
      a2 += p4.x * hB.y + p4.y * hB.x + p4.z * hA.w + p4.w * hA.z;
      a3 += p4.x * hB.z + p4.y * hB.y + p4.z * hB.x + p4.w * hA.w;
    }
  }
  *(float4*)(part + (tid << 2)) = make_float4(a0, a1, a2, a3);
  __syncthreads();
  if (tid < 32) {
    float s = Dp[0] * ps[t0 + tid];
    const int o4 = tid >> 2, oc = tid & 3;
#pragma unroll
    for (int wvi = 0; wvi < 8; ++wvi)
#pragma unroll
      for (int kgi = 0; kgi < 8; ++kgi)
        s += part[(((wvi << 6) + (kgi << 3) + o4) << 2) + oc];
    svs[tid] = s;
  }
  __syncthreads();

  // epilogue: wave wv streams rows 4*wv..4*wv+3
  float4 wa = *(const float4*)(Wout + ln * 8);
  float4 wb = *(const float4*)(Wout + ln * 8 + 4);
  const size_t rowbase = ((size_t)(b << 12) + (size_t)t0) * 512 + (size_t)ln * 8;
#pragma unroll
  for (int r4 = 0; r4 < 4; ++r4) {
    const int r = (wv << 2) + r4;
    float s = svs[r];
    float* op = out + rowbase + (size_t)r * 512;
    *(float4*)op = make_float4(s * wa.x, s * wa.y, s * wa.z, s * wa.w);
    *(float4*)(op + 4) = make_float4(s * wb.x, s * wb.y, s * wb.z, s * wb.w);
  }
}

extern "C" void kernel_launch(void* const* d_in, const int* in_sizes, int n_in,
                              void* d_out, int out_size, void* d_ws, size_t ws_size,
                              hipStream_t stream) {
  const float* u = (const float*)d_in[0];
  const float* A = (const float*)d_in[1];
  const float* B = (const float*)d_in[2];
  const float* C = (const float*)d_in[3];
  const float* D = (const float*)d_in[4];
  const float* logdt = (const float*)d_in[5];
  const float* Win = (const float*)d_in[6];
  const float* Wout = (const float*)d_in[7];
  float* outp = (float*)d_out;
  float* p_ws = (float*)d_ws;        // 65536 floats
  float* h_ws = p_ws + 65536;        // 4096 floats

  s4_k1<<<2049, 256, 0, stream>>>(u, A, B, C, logdt, Win, p_ws, h_ws);
  s4_co<<<2048, 512, 0, stream>>>(p_ws, h_ws, D, Wout, outp);
}